// Round 1
// 501.160 us; speedup vs baseline: 1.0835x; 1.0835x over previous
//
#include <hip/hip_runtime.h>
#include <cstdint>
#include <cstddef>

typedef _Float16 f16;
typedef _Float16 half8 __attribute__((ext_vector_type(8)));
typedef float floatx4 __attribute__((ext_vector_type(4)));
typedef unsigned short ushort8 __attribute__((ext_vector_type(8)));

// async global->LDS, 16B per lane. LDS dest = wave-uniform base + lane*16.
__device__ __forceinline__ void gload_lds16(const void* g, void* l) {
    __builtin_amdgcn_global_load_lds(
        (const __attribute__((address_space(1))) void*)g,
        (__attribute__((address_space(3))) void*)l,
        16, 0, 0);
}

// f32 -> bf16 with round-to-nearest-even (bit trick; e>=0, finite here)
__device__ __forceinline__ unsigned short f32_to_bf16(float f) {
    unsigned u = __float_as_uint(f);
    return (unsigned short)((u + 0x7FFFu + ((u >> 16) & 1u)) >> 16);
}
__device__ __forceinline__ float bf16_to_f32(unsigned short h) {
    return __uint_as_float(((unsigned)h) << 16);
}

// ---------------- K0a: f32 -> f16 convert (8 elems/thread) ----------------
__global__ void k_cvt(const float* __restrict__ src, f16* __restrict__ dst, int n8) {
    int i = blockIdx.x * blockDim.x + threadIdx.x;
    if (i >= n8) return;
    const float4* s = (const float4*)src + 2 * (size_t)i;
    float4 a = s[0], b = s[1];
    half8 h;
    h[0] = (f16)a.x; h[1] = (f16)a.y; h[2] = (f16)a.z; h[3] = (f16)a.w;
    h[4] = (f16)b.x; h[5] = (f16)b.y; h[6] = (f16)b.z; h[7] = (f16)b.w;
    ((half8*)dst)[i] = h;
}

// ------- K0b: h_s f32 -> h_s16 (same layout) + h_sT16 (d-major transpose) -------
__global__ void k_hs(const float* __restrict__ hs, f16* __restrict__ hs16, f16* __restrict__ hsT) {
    // grid: B * (S/64) * (D/64) = 4*64*4 = 1024
    int id = blockIdx.x;
    int dt = id & 3;
    int st = (id >> 2) & 63;
    int b  = id >> 8;
    __shared__ f16 tile[64][65];
    int t = threadIdx.x;
    int s0 = st * 64, d0 = dt * 64;
#pragma unroll
    for (int i = 0; i < 16; i++) {
        int e = t + i * 256;
        int r = e >> 6, c = e & 63;
        float v = hs[((size_t)(b * 4096 + s0 + r)) * 256 + d0 + c];
        f16 hv = (f16)v;
        hs16[((size_t)(b * 4096 + s0 + r)) * 256 + d0 + c] = hv;
        tile[r][c] = hv;
    }
    __syncthreads();
#pragma unroll
    for (int i = 0; i < 16; i++) {
        int e = t + i * 256;
        int r = e >> 6, c = e & 63;  // r = d-local, c = s-local
        hsT[((size_t)(b * 256 + d0 + r)) * 4096 + s0 + c] = tile[c][r];
    }
}

// ---------------- K1: energy = h_s @ W^T  (M=4096 s, N=256 t, K=256) -> f16 ----------------
__global__ __launch_bounds__(256, 2) void k_energy(
    const f16* __restrict__ A,    // h_s16: B*4096*256 (K-contig)
    const f16* __restrict__ Bt,   // W16: 256*256 (N,K) row-major
    f16* __restrict__ C)          // energy16: B*4096*256 (s-major, tgt-contig)
{
    int id = blockIdx.x;
    int tn = id & 1, tm = (id >> 1) & 31, b = id >> 6;
    const f16* Ab = A + (size_t)b * 4096 * 256;

    __shared__ __align__(16) f16 As[128 * 64];
    __shared__ __align__(16) f16 Bs[128 * 64];

    int tid = threadIdx.x;
    int wave = tid >> 6, lane = tid & 63;
    int wr = wave >> 1, wc = wave & 1;
    int lm = lane & 15, lq = lane >> 4;

    floatx4 acc[4][4] = {};
    int r0 = tm * 128, c0 = tn * 128;

    for (int k0 = 0; k0 < 256; k0 += 64) {
#pragma unroll
        for (int i = 0; i < 4; i++) {
            int rbase = wave * 32 + i * 8;
            int row = rbase + (lane >> 3);
            gload_lds16(Ab + (size_t)(r0 + row) * 256 + k0 + (lane & 7) * 8, &As[rbase * 64]);
            gload_lds16(Bt + (size_t)(c0 + row) * 256 + k0 + (lane & 7) * 8, &Bs[rbase * 64]);
        }
        __syncthreads();
        half8 af[4][2], bf[4][2];
#pragma unroll
        for (int mi = 0; mi < 4; mi++)
#pragma unroll
            for (int kk = 0; kk < 2; kk++) {
                af[mi][kk] = *(const half8*)&As[(wr * 64 + mi * 16 + lm) * 64 + kk * 32 + lq * 8];
                bf[mi][kk] = *(const half8*)&Bs[(wc * 64 + mi * 16 + lm) * 64 + kk * 32 + lq * 8];
            }
#pragma unroll
        for (int kk = 0; kk < 2; kk++)
#pragma unroll
            for (int mi = 0; mi < 4; mi++)
#pragma unroll
                for (int ni = 0; ni < 4; ni++)
                    acc[mi][ni] = __builtin_amdgcn_mfma_f32_16x16x32_f16(af[mi][kk], bf[ni][kk], acc[mi][ni], 0, 0, 0);
        __syncthreads();
    }
#pragma unroll
    for (int mi = 0; mi < 4; mi++)
#pragma unroll
        for (int ni = 0; ni < 4; ni++)
#pragma unroll
            for (int r = 0; r < 4; r++) {
                int row = r0 + wr * 64 + mi * 16 + lq * 4 + r;
                int col = c0 + wc * 64 + ni * 16 + lm;
                C[(size_t)(b * 4096 + row) * 256 + col] = (f16)acc[mi][ni][r];
            }
}

// -------- K2: scores GEMM + mask -> store e=exp(score) as BF16; fused row sumexp atomics --------
// bf16 transport: full f32 exponent range (no max-subtract needed), half the write traffic.
__global__ __launch_bounds__(256, 2) void k_scores(
    const f16* __restrict__ A,    // h_t16
    const f16* __restrict__ Bt,   // energy16
    const int* __restrict__ ms,   // B*S
    unsigned short* __restrict__ E, // workspace: B*T*S bf16 (exp(masked score))
    float* __restrict__ rsum)     // B*T, pre-zeroed; Σ_s exp(s) per row (no max shift)
{
    int id = blockIdx.x;
    int tn = id & 31, tm = (id >> 5) & 31, b = id >> 10;
    const f16* Ab = A + (size_t)b * 4096 * 256;
    const f16* Bb = Bt + (size_t)b * 4096 * 256;

    __shared__ __align__(16) f16 As[128 * 64];
    __shared__ __align__(16) f16 Bs[128 * 64];

    int tid = threadIdx.x;
    int wave = tid >> 6, lane = tid & 63;
    int wr = wave >> 1, wc = wave & 1;
    int lm = lane & 15, lq = lane >> 4;

    floatx4 acc[4][4] = {};
    int r0 = tm * 128, c0 = tn * 128;

    for (int k0 = 0; k0 < 256; k0 += 64) {
#pragma unroll
        for (int i = 0; i < 4; i++) {
            int rbase = wave * 32 + i * 8;
            int row = rbase + (lane >> 3);
            gload_lds16(Ab + (size_t)(r0 + row) * 256 + k0 + (lane & 7) * 8, &As[rbase * 64]);
            gload_lds16(Bb + (size_t)(c0 + row) * 256 + k0 + (lane & 7) * 8, &Bs[rbase * 64]);
        }
        __syncthreads();
        half8 af[4][2], bf[4][2];
#pragma unroll
        for (int mi = 0; mi < 4; mi++)
#pragma unroll
            for (int kk = 0; kk < 2; kk++) {
                af[mi][kk] = *(const half8*)&As[(wr * 64 + mi * 16 + lm) * 64 + kk * 32 + lq * 8];
                bf[mi][kk] = *(const half8*)&Bs[(wc * 64 + mi * 16 + lm) * 64 + kk * 32 + lq * 8];
            }
#pragma unroll
        for (int kk = 0; kk < 2; kk++)
#pragma unroll
            for (int mi = 0; mi < 4; mi++)
#pragma unroll
                for (int ni = 0; ni < 4; ni++)
                    acc[mi][ni] = __builtin_amdgcn_mfma_f32_16x16x32_f16(af[mi][kk], bf[ni][kk], acc[mi][ni], 0, 0, 0);
        __syncthreads();
    }
    // epilogue: e = mask ? exp(score) : 0; store bf16(e), accumulate f32 row sums
    float rs[4][4] = {};  // [mi][r]
#pragma unroll
    for (int ni = 0; ni < 4; ni++) {
        int col = c0 + wc * 64 + ni * 16 + lm;
        int m = ms[b * 4096 + col];
#pragma unroll
        for (int mi = 0; mi < 4; mi++)
#pragma unroll
            for (int r = 0; r < 4; r++) {
                int row = r0 + wr * 64 + mi * 16 + lq * 4 + r;
                float e = m ? __expf(acc[mi][ni][r]) : 0.0f;
                E[(size_t)(b * 4096 + row) * 4096 + col] = f32_to_bf16(e);
                rs[mi][r] += e;
            }
    }
#pragma unroll
    for (int mi = 0; mi < 4; mi++)
#pragma unroll
        for (int r = 0; r < 4; r++) {
            float v = rs[mi][r];
#pragma unroll
            for (int off = 1; off < 16; off <<= 1)
                v += __shfl_xor(v, off, 16);
            if (lm == 0) {
                int row = r0 + wr * 64 + mi * 16 + lq * 4 + r;
                atomicAdd(&rsum[b * 4096 + row], v);
            }
        }
}

// ------- K4: p = bf16(e)*rinv -> write p f32 to out + context partial GEMM (split-K, f16 partials) -------
// tile 128 t x 256 d, s-range 1024, grid = 4*32*4 = 512.
// LDS B-tile uses chunked-XOR layout: chunk g (s/8) at g*4096 + (row ^ 2*(g&3))*16 bytes.
// Staging keeps global_load_lds by permuting per-lane global row: row = R + (lane ^ c).
__global__ __launch_bounds__(256, 2) void k_ctx(
    const f16* __restrict__ BtT,          // h_sT16: B*256*4096
    const unsigned short* __restrict__ E, // bf16 e in workspace
    float* __restrict__ P,                // d_out scores region: normalized p (f32)
    const float* __restrict__ rsum,
    f16* __restrict__ part)               // 4 * B*4096*256 f16
{
    int id = blockIdx.x;
    int ks = id & 3, tt = (id >> 2) & 31, b = id >> 7;
    int tid = threadIdx.x;
    int wave = tid >> 6, lane = tid & 63;
    int lm = lane & 15, lq = lane >> 4;

    __shared__ __align__(16) f16 Bs[8 * 2048];  // 32KB chunked-swizzled

    int t0 = tt * 128;
    const f16* Bb = BtT + (size_t)b * 256 * 4096;

    float rinv[2];
    size_t rowbase[2];
#pragma unroll
    for (int mi = 0; mi < 2; mi++) {
        int row = t0 + wave * 32 + mi * 16 + lm;
        int gr = b * 4096 + row;
        rinv[mi] = 1.0f / rsum[gr];
        rowbase[mi] = (size_t)gr * 4096;
    }

    // staging: this wave fills chunks g0,g1; lane's global row is XOR-permuted
    int g0 = wave * 2, g1 = wave * 2 + 1;
    int c0g = 2 * (g0 & 3), c1g = 2 * (g1 & 3);
    const f16* gp0 = Bb + (size_t)(lane ^ c0g) * 4096 + g0 * 8;
    const f16* gp1 = Bb + (size_t)(lane ^ c1g) * 4096 + g1 * 8;
    f16* lb0 = &Bs[g0 * 2048];
    f16* lb1 = &Bs[g1 * 2048];

    // read-side lane bases (f16 elements): chunk (kk*4+lq), slot (lm ^ 2lq)
    int rbk[2];
    rbk[0] = (0 * 4 + lq) * 2048 + (lm ^ (2 * lq)) * 8;
    rbk[1] = (1 * 4 + lq) * 2048 + (lm ^ (2 * lq)) * 8;

    floatx4 acc[2][16] = {};
    int sbeg = ks * 1024;

    for (int it = 0; it < 16; it++) {
        int s0 = sbeg + it * 64;
        // e-loads FIRST (bf16: one dwordx4 per (mi,kk))
        ushort8 ev[2][2];
#pragma unroll
        for (int mi = 0; mi < 2; mi++)
#pragma unroll
            for (int kk = 0; kk < 2; kk++)
                ev[mi][kk] = *(const ushort8*)(E + rowbase[mi] + s0 + kk * 32 + lq * 8);
        // async staging (4 R-blocks x 2 chunks per wave)
#pragma unroll
        for (int R = 0; R < 256; R += 64) {
            gload_lds16(gp0 + (size_t)R * 4096 + s0, lb0 + R * 8);
            gload_lds16(gp1 + (size_t)R * 4096 + s0, lb1 + R * 8);
        }
        // normalize into f16 fragments (p = bf16(e)*rinv, p <= 1 fits f16 exactly)
        half8 af[2][2];
#pragma unroll
        for (int mi = 0; mi < 2; mi++)
#pragma unroll
            for (int kk = 0; kk < 2; kk++) {
                half8 h;
#pragma unroll
                for (int j = 0; j < 8; j++) {
                    float f = bf16_to_f32(ev[mi][kk][j]) * rinv[mi];
                    h[j] = (f16)f;
                }
                af[mi][kk] = h;
            }
        __syncthreads();  // staging visible
        // write normalized p (f32) — stores fly during MFMA phase
#pragma unroll
        for (int mi = 0; mi < 2; mi++)
#pragma unroll
            for (int kk = 0; kk < 2; kk++) {
                float* p = P + rowbase[mi] + s0 + kk * 32 + lq * 8;
                half8 h = af[mi][kk];
                ((float4*)p)[0] = make_float4((float)h[0], (float)h[1], (float)h[2], (float)h[3]);
                ((float4*)p)[1] = make_float4((float)h[4], (float)h[5], (float)h[6], (float)h[7]);
            }
#pragma unroll
        for (int kk = 0; kk < 2; kk++)
#pragma unroll
            for (int ni = 0; ni < 16; ni++) {
                half8 bf = *(const half8*)&Bs[rbk[kk] + ni * 128];
#pragma unroll
                for (int mi = 0; mi < 2; mi++)
                    acc[mi][ni] = __builtin_amdgcn_mfma_f32_16x16x32_f16(af[mi][kk], bf, acc[mi][ni], 0, 0, 0);
            }
        __syncthreads();
    }

    f16* Pp = part + (size_t)ks * 4194304 + (size_t)b * 1048576;
#pragma unroll
    for (int mi = 0; mi < 2; mi++)
#pragma unroll
        for (int ni = 0; ni < 16; ni++)
#pragma unroll
            for (int r = 0; r < 4; r++) {
                int row = t0 + wave * 32 + mi * 16 + lq * 4 + r;
                int col = ni * 16 + lm;
                Pp[(size_t)row * 256 + col] = (f16)acc[mi][ni][r];
            }
}

// ---------------- K5: reduce 4 split-K f16 partials -> context f32 ----------------
__global__ void k_red(const f16* __restrict__ part, float* __restrict__ out) {
    size_t i = (size_t)blockIdx.x * 256 + threadIdx.x;  // half8 index, N8 = 524288
    const half8* p = (const half8*)part;
    half8 a = p[i];
    half8 b = p[i + 524288];
    half8 c = p[i + 1048576];
    half8 d = p[i + 1572864];
    float4 o0, o1;
    o0.x = (float)a[0] + (float)b[0] + (float)c[0] + (float)d[0];
    o0.y = (float)a[1] + (float)b[1] + (float)c[1] + (float)d[1];
    o0.z = (float)a[2] + (float)b[2] + (float)c[2] + (float)d[2];
    o0.w = (float)a[3] + (float)b[3] + (float)c[3] + (float)d[3];
    o1.x = (float)a[4] + (float)b[4] + (float)c[4] + (float)d[4];
    o1.y = (float)a[5] + (float)b[5] + (float)c[5] + (float)d[5];
    o1.z = (float)a[6] + (float)b[6] + (float)c[6] + (float)d[6];
    o1.w = (float)a[7] + (float)b[7] + (float)c[7] + (float)d[7];
    ((float4*)out)[2 * i] = o0;
    ((float4*)out)[2 * i + 1] = o1;
}

extern "C" void kernel_launch(void* const* d_in, const int* in_sizes, int n_in,
                              void* d_out, int out_size, void* d_ws, size_t ws_size,
                              hipStream_t stream) {
    const float* h_t = (const float*)d_in[0];   // 4*4096*256
    const float* h_s = (const float*)d_in[1];   // 4*4096*256
    const int*   m_s = (const int*)d_in[2];     // 4*4096
    const float* W   = (const float*)d_in[3];   // 256*256

    float* out = (float*)d_out;
    char* ws = (char*)d_ws;
    f16* h_t16 = (f16*)(ws);                      // 8.39 MB
    f16* h_s16 = (f16*)(ws + 8388608);            // 8.39 MB
    f16* h_sT  = (f16*)(ws + 16777216);           // 8.39 MB
    f16* en16  = (f16*)(ws + 25165824);           // 8.39 MB
    f16* W16   = (f16*)(ws + 33554432);           // 128 KB
    float* rsum = (float*)(ws + 33685504);        // 64 KB
    unsigned short* e16 = (unsigned short*)(ws + 33751040);  // 134.2 MB bf16 e
    f16* part = (f16*)(ws + 167968768);           // 33.6 MB f16 partials

    float* ctx = out;              // 4*4096*256 = 4194304
    float* sc  = out + 4194304;    // 4*4096*4096

    hipMemsetAsync(rsum, 0, 16384 * sizeof(float), stream);
    k_cvt<<<2048, 256, 0, stream>>>(h_t, h_t16, 524288);
    k_cvt<<<32, 256, 0, stream>>>(W, W16, 8192);
    k_hs<<<1024, 256, 0, stream>>>(h_s, h_s16, h_sT);
    k_energy<<<256, 256, 0, stream>>>(h_s16, W16, en16);
    k_scores<<<4096, 256, 0, stream>>>(h_t16, en16, m_s, e16, rsum);
    k_ctx<<<512, 256, 0, stream>>>(h_sT, e16, sc, rsum, part);
    k_red<<<2048, 256, 0, stream>>>(part, ctx);
}